// Round 5
// baseline (208.797 us; speedup 1.0000x reference)
//
#include <hip/hip_runtime.h>
#include <hip/hip_cooperative_groups.h>

namespace cg = cooperative_groups;

#define SCALE_F 512.0f

// ws layout (float offsets)
#define WS_H     0        // B*S*E = 131072 floats
#define WS_GPART 131072   // 2048 chunks * 8 experts = 16384 floats
#define WS_SELC  147456   // 8 ints (sel) + 8 floats (coef)  (fallback path)

// ================= Cooperative fused kernel =================
// Grid-stride over 2048 chunks of 8 tokens. Wave w owns weight rows 4w..4w+3
// (rows 0..7 = lora_A experts, 8..15 = gate_w experts).
// Phase 1: per chunk -> h[tok][0..7] to global, gate partials -> gpart[chunk][8].
// grid.sync(). Phase 2: wave w reduces batch w's gpart slice -> sel/coef for all
// 4 batches in LDS; then grid-stride combine + write out.
__global__ __launch_bounds__(256) void fused_moe(
    const float* __restrict__ x, const float* __restrict__ lora_A,
    const float* __restrict__ lora_B, const float* __restrict__ gate_w,
    const float* __restrict__ gate_b, float* __restrict__ out,
    float* __restrict__ h, float* __restrict__ gpart)
{
    const int tid  = threadIdx.x;
    const int w    = tid >> 6;
    const int lane = tid & 63;
    const int grid = gridDim.x;

    __shared__ float  xbuf[8 * 1024];      // 32 KB staging (8 token rows)
    __shared__ float4 s_gred[4][2];        // per-batch gate sums (e0-3, e4-7)
    __shared__ int    s_sel[4][2];
    __shared__ float  s_coef[4][2];

    // Wave's 4 weight rows in registers: float4 idx lane+64j.
    float4 W[4][4];
#pragma unroll
    for (int rr = 0; rr < 4; ++rr) {
        const int row = 4 * w + rr;
        const float* rp = (row < 8) ? (lora_A + row * 1024)
                                    : (gate_w + (row - 8) * 1024);
        const float4* rp4 = (const float4*)rp;
#pragma unroll
        for (int j = 0; j < 4; ++j) W[rr][j] = rp4[lane + 64 * j];
    }

    // ---- Phase 1: h + gate partials per 8-token chunk
    for (int c = blockIdx.x; c < 2048; c += grid) {
        const int tok0 = c * 8;
        const float4* src = (const float4*)(x + (size_t)tok0 * 1024);
        float4* dst = (float4*)xbuf;
#pragma unroll
        for (int j = 0; j < 8; ++j) dst[tid + 256 * j] = src[tid + 256 * j];
        __syncthreads();

        float g0 = 0.f, g1 = 0.f, g2 = 0.f, g3 = 0.f;

#pragma unroll 2
        for (int t = 0; t < 8; ++t) {
            const float4* xr = (const float4*)(xbuf + t * 1024);
            const float4 xv0 = xr[lane];
            const float4 xv1 = xr[lane + 64];
            const float4 xv2 = xr[lane + 128];
            const float4 xv3 = xr[lane + 192];

            float p[4];
#pragma unroll
            for (int rr = 0; rr < 4; ++rr) {
                const float4 a0 = W[rr][0], a1 = W[rr][1];
                const float4 a2 = W[rr][2], a3 = W[rr][3];
                float s;
                s  = xv0.x * a0.x + xv0.y * a0.y + xv0.z * a0.z + xv0.w * a0.w;
                s += xv1.x * a1.x + xv1.y * a1.y + xv1.z * a1.z + xv1.w * a1.w;
                s += xv2.x * a2.x + xv2.y * a2.y + xv2.z * a2.z + xv2.w * a2.w;
                s += xv3.x * a3.x + xv3.y * a3.y + xv3.z * a3.z + xv3.w * a3.w;
                p[rr] = s;
            }
#pragma unroll
            for (int off = 32; off > 0; off >>= 1) {
                p[0] += __shfl_xor(p[0], off);
                p[1] += __shfl_xor(p[1], off);
                p[2] += __shfl_xor(p[2], off);
                p[3] += __shfl_xor(p[3], off);
            }
            if (w < 2) {
                if (lane == 0) {
                    *(float4*)(h + (size_t)(tok0 + t) * 8 + w * 4) =
                        make_float4(p[0], p[1], p[2], p[3]);
                }
            } else {
                g0 += p[0]; g1 += p[1]; g2 += p[2]; g3 += p[3];
            }
        }
        if (w >= 2 && lane == 0) {
            *(float4*)(gpart + (size_t)c * 8 + (w - 2) * 4) =
                make_float4(g0, g1, g2, g3);
        }
        __syncthreads();   // xbuf reused next iteration
    }

    __threadfence();
    cg::this_grid().sync();

    // ---- Phase 2a: wave w reduces batch w (512 chunk-rows = 1024 float4)
    {
        const float4* gp4 = (const float4*)(gpart + (size_t)w * 4096);
        float4 acc = make_float4(0.f, 0.f, 0.f, 0.f);
#pragma unroll
        for (int q = 0; q < 16; ++q) {
            const float4 v = gp4[lane + 64 * q];   // parity(lane+64q)==parity(lane)
            acc.x += v.x; acc.y += v.y; acc.z += v.z; acc.w += v.w;
        }
#pragma unroll
        for (int off = 2; off <= 32; off <<= 1) {
            acc.x += __shfl_xor(acc.x, off);
            acc.y += __shfl_xor(acc.y, off);
            acc.z += __shfl_xor(acc.z, off);
            acc.w += __shfl_xor(acc.w, off);
        }
        if (lane < 2) s_gred[w][lane] = acc;   // lane0: e0-3, lane1: e4-7
    }
    __syncthreads();

    if (tid < 4) {                              // thread tid = batch tid
        const float4 lo = s_gred[tid][0];
        const float4 hi = s_gred[tid][1];
        float l[8] = { lo.x, lo.y, lo.z, lo.w, hi.x, hi.y, hi.z, hi.w };
#pragma unroll
        for (int e = 0; e < 8; ++e) l[e] = l[e] * (1.0f / 4096.0f) + gate_b[e];
        float m = l[0];
#pragma unroll
        for (int e = 1; e < 8; ++e) m = fmaxf(m, l[e]);
        float sum = 0.f;
#pragma unroll
        for (int e = 0; e < 8; ++e) { l[e] = expf(l[e] - m); sum += l[e]; }
        const float inv = 1.0f / sum;

        int i0 = 0;
#pragma unroll
        for (int e = 1; e < 8; ++e) if (l[e] > l[i0]) i0 = e;
        int i1 = (i0 == 0) ? 1 : 0;
#pragma unroll
        for (int e = 0; e < 8; ++e) if (e != i0 && l[e] > l[i1]) i1 = e;

        s_sel[tid][0]  = i0;
        s_sel[tid][1]  = i1;
        s_coef[tid][0] = SCALE_F * l[i0] * inv;
        s_coef[tid][1] = SCALE_F * l[i1] * inv;
    }
    __syncthreads();

    // ---- Phase 2b: combine + write out, grid-stride over the same chunks
    for (int c = blockIdx.x; c < 2048; c += grid) {
        const int bb = c >> 9;                  // 512 chunks per batch
        const int   i0 = s_sel[bb][0];
        const int   i1 = s_sel[bb][1];
        const float c0 = s_coef[bb][0];
        const float c1 = s_coef[bb][1];

        const float4 b0 = ((const float4*)(lora_B + i0 * 1024))[tid];
        const float4 b1 = ((const float4*)(lora_B + i1 * 1024))[tid];
        const float4 v0 = make_float4(c0 * b0.x, c0 * b0.y, c0 * b0.z, c0 * b0.w);
        const float4 v1 = make_float4(c1 * b1.x, c1 * b1.y, c1 * b1.z, c1 * b1.w);

        const int tok0 = c * 8;
        float4* out4 = (float4*)out;
#pragma unroll 2
        for (int t = 0; t < 8; ++t) {
            const int tok = tok0 + t;
            const float h0 = h[(size_t)tok * 8 + i0];
            const float h1 = h[(size_t)tok * 8 + i1];
            float4 r;
            r.x = h0 * v0.x + h1 * v1.x;
            r.y = h0 * v0.y + h1 * v1.y;
            r.z = h0 * v0.z + h1 * v1.z;
            r.w = h0 * v0.w + h1 * v1.w;
            out4[(size_t)tok * 256 + tid] = r;
        }
    }
}

// ================= Fallback path: proven R3 three-kernel pipeline =================
__global__ __launch_bounds__(256) void k1_h_gate(
    const float* __restrict__ x, const float* __restrict__ lora_A,
    const float* __restrict__ gate_w, float* __restrict__ h,
    float* __restrict__ gpart)
{
    const int tid  = threadIdx.x;
    const int w    = tid >> 6;
    const int lane = tid & 63;
    const int tok0 = blockIdx.x * 8;

    __shared__ float xbuf[8 * 1024];

    float4 W[4][4];
#pragma unroll
    for (int rr = 0; rr < 4; ++rr) {
        const int row = 4 * w + rr;
        const float* rp = (row < 8) ? (lora_A + row * 1024)
                                    : (gate_w + (row - 8) * 1024);
        const float4* rp4 = (const float4*)rp;
#pragma unroll
        for (int j = 0; j < 4; ++j) W[rr][j] = rp4[lane + 64 * j];
    }

    const float4* src = (const float4*)(x + (size_t)tok0 * 1024);
    float4* dst = (float4*)xbuf;
#pragma unroll
    for (int j = 0; j < 8; ++j) dst[tid + 256 * j] = src[tid + 256 * j];
    __syncthreads();

    float g0 = 0.f, g1 = 0.f, g2 = 0.f, g3 = 0.f;

#pragma unroll 2
    for (int t = 0; t < 8; ++t) {
        const float4* xr = (const float4*)(xbuf + t * 1024);
        const float4 xv0 = xr[lane];
        const float4 xv1 = xr[lane + 64];
        const float4 xv2 = xr[lane + 128];
        const float4 xv3 = xr[lane + 192];

        float p[4];
#pragma unroll
        for (int rr = 0; rr < 4; ++rr) {
            const float4 a0 = W[rr][0], a1 = W[rr][1];
            const float4 a2 = W[rr][2], a3 = W[rr][3];
            float s;
            s  = xv0.x * a0.x + xv0.y * a0.y + xv0.z * a0.z + xv0.w * a0.w;
            s += xv1.x * a1.x + xv1.y * a1.y + xv1.z * a1.z + xv1.w * a1.w;
            s += xv2.x * a2.x + xv2.y * a2.y + xv2.z * a2.z + xv2.w * a2.w;
            s += xv3.x * a3.x + xv3.y * a3.y + xv3.z * a3.z + xv3.w * a3.w;
            p[rr] = s;
        }
#pragma unroll
        for (int off = 32; off > 0; off >>= 1) {
            p[0] += __shfl_xor(p[0], off);
            p[1] += __shfl_xor(p[1], off);
            p[2] += __shfl_xor(p[2], off);
            p[3] += __shfl_xor(p[3], off);
        }
        const int tok = tok0 + t;
        if (w < 2) {
            if (lane == 0) {
                *(float4*)(h + (size_t)tok * 8 + w * 4) =
                    make_float4(p[0], p[1], p[2], p[3]);
            }
        } else {
            g0 += p[0]; g1 += p[1]; g2 += p[2]; g3 += p[3];
        }
    }

    if (w >= 2 && lane == 0) {
        *(float4*)(gpart + (size_t)blockIdx.x * 8 + (w - 2) * 4) =
            make_float4(g0, g1, g2, g3);
    }
}

__global__ __launch_bounds__(256) void k2_gate(
    const float* __restrict__ gpart, const float* __restrict__ gate_b,
    int* __restrict__ sel, float* __restrict__ coef)
{
    const int tid  = threadIdx.x;
    const int j    = tid & 7;
    const int pair = tid >> 3;
    const int b    = pair >> 3;
    const int e    = pair & 7;

    __shared__ float s_red[32][8];
    __shared__ float s_logit[32];

    float acc = 0.f;
#pragma unroll 8
    for (int k = 0; k < 64; ++k) {
        acc += gpart[(size_t)(b * 512 + j * 64 + k) * 8 + e];
    }
    s_red[pair][j] = acc;
    __syncthreads();

    if (j == 0) {
        float s = 0.f;
#pragma unroll
        for (int q = 0; q < 8; ++q) s += s_red[pair][q];
        s_logit[pair] = s * (1.0f / 4096.0f) + gate_b[e];
    }
    __syncthreads();

    if (tid < 4) {
        float sc[8];
        float m = -1e30f;
#pragma unroll
        for (int q = 0; q < 8; ++q) { sc[q] = s_logit[tid * 8 + q]; m = fmaxf(m, sc[q]); }
        float sum = 0.f;
#pragma unroll
        for (int q = 0; q < 8; ++q) { sc[q] = expf(sc[q] - m); sum += sc[q]; }
        const float inv = 1.0f / sum;

        int i0 = 0;
#pragma unroll
        for (int q = 1; q < 8; ++q) if (sc[q] > sc[i0]) i0 = q;
        int i1 = (i0 == 0) ? 1 : 0;
#pragma unroll
        for (int q = 0; q < 8; ++q) if (q != i0 && sc[q] > sc[i1]) i1 = q;

        sel[tid * 2]      = i0;
        sel[tid * 2 + 1]  = i1;
        coef[tid * 2]     = SCALE_F * sc[i0] * inv;
        coef[tid * 2 + 1] = SCALE_F * sc[i1] * inv;
    }
}

__global__ __launch_bounds__(256) void k3_combine(
    const float* __restrict__ h, const int* __restrict__ sel,
    const float* __restrict__ coef, const float* __restrict__ lora_B,
    float* __restrict__ out)
{
    const int tid = threadIdx.x;
    const int blk = blockIdx.x;
    const int b   = blk >> 9;

    const int   i0 = sel[b * 2];
    const int   i1 = sel[b * 2 + 1];
    const float c0 = coef[b * 2];
    const float c1 = coef[b * 2 + 1];

    const float4 b0 = ((const float4*)(lora_B + i0 * 1024))[tid];
    const float4 b1 = ((const float4*)(lora_B + i1 * 1024))[tid];
    const float4 v0 = make_float4(c0 * b0.x, c0 * b0.y, c0 * b0.z, c0 * b0.w);
    const float4 v1 = make_float4(c1 * b1.x, c1 * b1.y, c1 * b1.z, c1 * b1.w);

    const int tok0 = blk * 8;
    float4* out4 = (float4*)out;
#pragma unroll
    for (int t = 0; t < 8; ++t) {
        const int tok = tok0 + t;
        const float h0 = h[(size_t)tok * 8 + i0];
        const float h1 = h[(size_t)tok * 8 + i1];
        float4 r;
        r.x = h0 * v0.x + h1 * v1.x;
        r.y = h0 * v0.y + h1 * v1.y;
        r.z = h0 * v0.z + h1 * v1.z;
        r.w = h0 * v0.w + h1 * v1.w;
        out4[(size_t)tok * 256 + tid] = r;
    }
}

extern "C" void kernel_launch(void* const* d_in, const int* in_sizes, int n_in,
                              void* d_out, int out_size, void* d_ws, size_t ws_size,
                              hipStream_t stream) {
    const float* x      = (const float*)d_in[0];
    const float* lora_A = (const float*)d_in[1];
    const float* lora_B = (const float*)d_in[2];
    const float* gate_w = (const float*)d_in[3];
    const float* gate_b = (const float*)d_in[4];
    float* out = (float*)d_out;

    float* ws    = (float*)d_ws;
    float* h     = ws + WS_H;
    float* gpart = ws + WS_GPART;
    int*   sel   = (int*)(ws + WS_SELC);
    float* coef  = ws + WS_SELC + 8;

    // Size the cooperative grid from the runtime's own occupancy calculation.
    int dev = 0;
    (void)hipGetDevice(&dev);
    int numCU = 0;
    (void)hipDeviceGetAttribute(&numCU, hipDeviceAttributeMultiprocessorCount, dev);
    int maxBlk = 0;
    hipError_t occ_err = hipOccupancyMaxActiveBlocksPerMultiprocessor(
        &maxBlk, fused_moe, 256, 0);

    hipError_t coop_err = hipErrorUnknown;
    if (occ_err == hipSuccess && numCU > 0 && maxBlk > 0) {
        int grid = maxBlk * numCU;
        if (grid > 2048) grid = 2048;
        if (grid >= 64) {
            void* kargs[] = {
                (void*)&x, (void*)&lora_A, (void*)&lora_B, (void*)&gate_w,
                (void*)&gate_b, (void*)&out, (void*)&h, (void*)&gpart
            };
            coop_err = hipLaunchCooperativeKernel((const void*)fused_moe,
                                                  dim3(grid), dim3(256),
                                                  kargs, 0, stream);
        }
    }

    if (coop_err != hipSuccess) {
        // Proven three-kernel fallback (R3 structure).
        k1_h_gate<<<2048, 256, 0, stream>>>(x, lora_A, gate_w, h, gpart);
        k2_gate<<<1, 256, 0, stream>>>(gpart, gate_b, sel, coef);
        k3_combine<<<2048, 256, 0, stream>>>(h, sel, coef, lora_B, out);
    }
}

// Round 6
// 154.751 us; speedup vs baseline: 1.3492x; 1.3492x over previous
//
#include <hip/hip_runtime.h>

#define SCALE_F 512.0f

// ws layout (float offsets)
#define WS_H     0         // B*S*E = 131072 floats (512 KB)
#define WS_PCOL  131072    // 2048 blocks * 1024 col-sums = 2097152 floats (8 MB)
#define WS_SELC  2228224   // 8 ints (sel) + 8 floats (coef)

// ---------------- Kernel 1: h[tok][0..7] + per-block column-sums of x
// grid 2048 x 256; 8 tokens/block (32 KB LDS). Wave w: row group g=w&1
// (lora_A rows 4g..4g+3), token half th=w>>1 (tokens th*4..th*4+3).
// Gate logits NOT computed here: during staging each thread accumulates its
// float4-column over the 8 staged rows -> pcol[blk][1024] (gating needs only
// the segment mean: logits = (sum_s x) . gw / 4096).
__global__ __launch_bounds__(256) void k1_h_colsum(
    const float* __restrict__ x, const float* __restrict__ lora_A,
    float* __restrict__ h, float* __restrict__ pcol)
{
    const int tid  = threadIdx.x;
    const int w    = tid >> 6;
    const int lane = tid & 63;
    const int g    = w & 1;          // row group
    const int th   = w >> 1;         // token half
    const int tok0 = blockIdx.x * 8;

    __shared__ float xbuf[8 * 1024];   // 32 KB

    // Wave's 4 lora_A rows in registers: float4 idx lane+64j.
    float4 W[4][4];
#pragma unroll
    for (int rr = 0; rr < 4; ++rr) {
        const float4* rp4 = (const float4*)(lora_A + (size_t)(4 * g + rr) * 1024);
#pragma unroll
        for (int j = 0; j < 4; ++j) W[rr][j] = rp4[lane + 64 * j];
    }

    // Stage 8 token rows (2048 float4, coalesced) + free column-sum:
    // thread tid touches float4-column `tid` of every staged row.
    const float4* src = (const float4*)(x + (size_t)tok0 * 1024);
    float4* dst = (float4*)xbuf;
    float4 csum = make_float4(0.f, 0.f, 0.f, 0.f);
#pragma unroll
    for (int j = 0; j < 8; ++j) {
        const float4 v = src[tid + 256 * j];
        dst[tid + 256 * j] = v;
        csum.x += v.x; csum.y += v.y; csum.z += v.z; csum.w += v.w;
    }
    ((float4*)(pcol + (size_t)blockIdx.x * 1024))[tid] = csum;
    __syncthreads();

    // Each wave: 4 tokens x 4 rows.
#pragma unroll 2
    for (int t = 0; t < 4; ++t) {
        const int trow = th * 4 + t;
        const float4* xr = (const float4*)(xbuf + trow * 1024);
        const float4 xv0 = xr[lane];
        const float4 xv1 = xr[lane + 64];
        const float4 xv2 = xr[lane + 128];
        const float4 xv3 = xr[lane + 192];

        float p[4];
#pragma unroll
        for (int rr = 0; rr < 4; ++rr) {
            const float4 a0 = W[rr][0], a1 = W[rr][1];
            const float4 a2 = W[rr][2], a3 = W[rr][3];
            float s;
            s  = xv0.x * a0.x + xv0.y * a0.y + xv0.z * a0.z + xv0.w * a0.w;
            s += xv1.x * a1.x + xv1.y * a1.y + xv1.z * a1.z + xv1.w * a1.w;
            s += xv2.x * a2.x + xv2.y * a2.y + xv2.z * a2.z + xv2.w * a2.w;
            s += xv3.x * a3.x + xv3.y * a3.y + xv3.z * a3.z + xv3.w * a3.w;
            p[rr] = s;
        }
#pragma unroll
        for (int off = 32; off > 0; off >>= 1) {
            p[0] += __shfl_xor(p[0], off);
            p[1] += __shfl_xor(p[1], off);
            p[2] += __shfl_xor(p[2], off);
            p[3] += __shfl_xor(p[3], off);
        }
        if (lane == 0) {
            *(float4*)(h + (size_t)(tok0 + trow) * 8 + g * 4) =
                make_float4(p[0], p[1], p[2], p[3]);
        }
    }
}

// ---------------- Kernel 2: reduce column partials -> seg sum, gate dots,
// softmax, top-2. 4 blocks (one per batch) x 256 thr.
__global__ __launch_bounds__(256) void k2_gate(
    const float* __restrict__ pcol, const float* __restrict__ gate_w,
    const float* __restrict__ gate_b, int* __restrict__ sel,
    float* __restrict__ coef)
{
    const int tid  = threadIdx.x;
    const int w    = tid >> 6;
    const int lane = tid & 63;
    const int b    = blockIdx.x;

    __shared__ float s_seg[1024];
    __shared__ float s_logit[8];

    // Reduce this batch's 512 block-partials (2 MB, coalesced, L2/L3).
    const float4* pc4 = (const float4*)pcol + (size_t)b * 512 * 256;
    float4 acc = make_float4(0.f, 0.f, 0.f, 0.f);
#pragma unroll 8
    for (int p = 0; p < 512; ++p) {
        const float4 v = pc4[(size_t)p * 256 + tid];
        acc.x += v.x; acc.y += v.y; acc.z += v.z; acc.w += v.w;
    }
    ((float4*)s_seg)[tid] = acc;
    __syncthreads();

    // Wave w dots experts 2w, 2w+1 against the segment sum.
    {
        const float4* sg4 = (const float4*)s_seg;
        const float4* w0p = (const float4*)(gate_w + (size_t)(2 * w) * 1024);
        const float4* w1p = (const float4*)(gate_w + (size_t)(2 * w + 1) * 1024);
        float p0 = 0.f, p1 = 0.f;
#pragma unroll
        for (int j = 0; j < 4; ++j) {
            const float4 sv = sg4[lane + 64 * j];
            const float4 w0 = w0p[lane + 64 * j];
            const float4 w1 = w1p[lane + 64 * j];
            p0 += sv.x * w0.x + sv.y * w0.y + sv.z * w0.z + sv.w * w0.w;
            p1 += sv.x * w1.x + sv.y * w1.y + sv.z * w1.z + sv.w * w1.w;
        }
#pragma unroll
        for (int off = 32; off > 0; off >>= 1) {
            p0 += __shfl_xor(p0, off);
            p1 += __shfl_xor(p1, off);
        }
        if (lane == 0) {
            s_logit[2 * w]     = p0;
            s_logit[2 * w + 1] = p1;
        }
    }
    __syncthreads();

    if (tid == 0) {
        float l[8];
#pragma unroll
        for (int e = 0; e < 8; ++e)
            l[e] = s_logit[e] * (1.0f / 4096.0f) + gate_b[e];
        float m = l[0];
#pragma unroll
        for (int e = 1; e < 8; ++e) m = fmaxf(m, l[e]);
        float sum = 0.f;
#pragma unroll
        for (int e = 0; e < 8; ++e) { l[e] = expf(l[e] - m); sum += l[e]; }
        const float inv = 1.0f / sum;

        int i0 = 0;
#pragma unroll
        for (int e = 1; e < 8; ++e) if (l[e] > l[i0]) i0 = e;
        int i1 = (i0 == 0) ? 1 : 0;
#pragma unroll
        for (int e = 0; e < 8; ++e) if (e != i0 && l[e] > l[i1]) i1 = e;

        sel[b * 2]      = i0;
        sel[b * 2 + 1]  = i1;
        coef[b * 2]     = SCALE_F * l[i0] * inv;
        coef[b * 2 + 1] = SCALE_F * l[i1] * inv;
    }
}

// ---------------- Kernel 3: out[tok,o] = c0*h0*B[i0,o] + c1*h1*B[i1,o]
// grid 4096 x 256; 4 tokens/block for write parallelism.
__global__ __launch_bounds__(256) void k3_combine(
    const float* __restrict__ h, const int* __restrict__ sel,
    const float* __restrict__ coef, const float* __restrict__ lora_B,
    float* __restrict__ out)
{
    const int tid = threadIdx.x;
    const int blk = blockIdx.x;
    const int b   = blk >> 10;               // 1024 blocks per batch

    const int   i0 = sel[b * 2];
    const int   i1 = sel[b * 2 + 1];
    const float c0 = coef[b * 2];
    const float c1 = coef[b * 2 + 1];

    const float4 b0 = ((const float4*)(lora_B + (size_t)i0 * 1024))[tid];
    const float4 b1 = ((const float4*)(lora_B + (size_t)i1 * 1024))[tid];
    const float4 v0 = make_float4(c0 * b0.x, c0 * b0.y, c0 * b0.z, c0 * b0.w);
    const float4 v1 = make_float4(c1 * b1.x, c1 * b1.y, c1 * b1.z, c1 * b1.w);

    const int tok0 = blk * 4;
    float4* out4 = (float4*)out;
#pragma unroll
    for (int t = 0; t < 4; ++t) {
        const int tok = tok0 + t;
        const float h0 = h[(size_t)tok * 8 + i0];
        const float h1 = h[(size_t)tok * 8 + i1];
        float4 r;
        r.x = h0 * v0.x + h1 * v1.x;
        r.y = h0 * v0.y + h1 * v1.y;
        r.z = h0 * v0.z + h1 * v1.z;
        r.w = h0 * v0.w + h1 * v1.w;
        out4[(size_t)tok * 256 + tid] = r;
    }
}

extern "C" void kernel_launch(void* const* d_in, const int* in_sizes, int n_in,
                              void* d_out, int out_size, void* d_ws, size_t ws_size,
                              hipStream_t stream) {
    const float* x      = (const float*)d_in[0];
    const float* lora_A = (const float*)d_in[1];
    const float* lora_B = (const float*)d_in[2];
    const float* gate_w = (const float*)d_in[3];
    const float* gate_b = (const float*)d_in[4];
    float* out = (float*)d_out;

    float* ws   = (float*)d_ws;
    float* h    = ws + WS_H;
    float* pcol = ws + WS_PCOL;
    int*   sel  = (int*)(ws + WS_SELC);
    float* coef = ws + WS_SELC + 8;

    k1_h_colsum<<<2048, 256, 0, stream>>>(x, lora_A, h, pcol);
    k2_gate<<<4, 256, 0, stream>>>(pcol, gate_w, gate_b, sel, coef);
    k3_combine<<<4096, 256, 0, stream>>>(h, sel, coef, lora_B, out);
}